// Round 1
// baseline (545.308 us; speedup 1.0000x reference)
//
#include <hip/hip_runtime.h>
#include <hip/hip_bf16.h>

typedef __bf16 bf16;
typedef __bf16 bf16x8 __attribute__((ext_vector_type(8)));
typedef float f32x4 __attribute__((ext_vector_type(4)));
typedef float floatv4 __attribute__((ext_vector_type(4)));

#define QK_SCALE 0.17677669529663687f

// LDS row strides (elements) chosen so ds_read_b128 stays 16B-aligned and
// bank starts cycle over 8 distinct positions (2-way conflict = free).
#define QK_LD 40   // [64][40] per head (Q, K)
#define VT_LD 72   // [32][72] per head (V transposed)
#define P_LD  40   // [64][40] per wave, one 32-col chunk at a time
#define AO_LD 200  // [64][200]

struct SmemT {
    bf16 q[6][64][QK_LD];    // 30720 B
    bf16 k[6][64][QK_LD];    // 30720 B
    bf16 vt[6][32][VT_LD];   // 27648 B
    bf16 p[6][64][P_LD];     // 30720 B
    bf16 ao[64][AO_LD];      // 25600 B
};                           // total 145408 B (< 160 KiB)

// ---------------- pre-kernel: weight bf16 convert + rpb expand ----------------
__global__ void wmsa_prep(const float* __restrict__ qkv_w,
                          const float* __restrict__ out_w,
                          const float* __restrict__ rpb_table,
                          bf16* __restrict__ qkv_wb,
                          bf16* __restrict__ out_wb,
                          float* __restrict__ rpbx) {
    int t = blockIdx.x * 256 + threadIdx.x;
    if (t < 110592) qkv_wb[t] = (bf16)qkv_w[t];
    if (t < 36864)  out_wb[t] = (bf16)out_w[t];
    if (t < 14406) {
        int h = t / 2401, ij = t % 2401, i = ij / 49, j = ij % 49;
        int ri = (i / 7 - j / 7 + 6) * 13 + (i % 7 - j % 7 + 6);
        rpbx[t] = rpb_table[ri * 6 + h];
    }
}

// ---------------- main fused kernel: one window per block ----------------
__global__ __launch_bounds__(384, 1) void wmsa_main(
    const float* __restrict__ x, const float* __restrict__ mask,
    const float* __restrict__ qkv_b, const float* __restrict__ out_b,
    const bf16* __restrict__ qkv_wb, const bf16* __restrict__ out_wb,
    const float* __restrict__ rpbx, float* __restrict__ out)
{
    __shared__ SmemT sm;
    const int b    = blockIdx.x;
    const int tid  = threadIdx.x;
    const int wv   = tid >> 6;      // 0..5
    const int lane = tid & 63;
    const int lo   = lane & 15;
    const int hi   = lane >> 4;     // 0..3

    const float* xw = x + (size_t)b * (49 * 192);

    // ================= Phase 1: QKV = x @ qkv_w^T + qkv_b =================
    // A fragments (x rows, bf16), held in registers: 4 M-tiles x 6 K-steps.
    bf16x8 afr[4][6];
#pragma unroll
    for (int mi = 0; mi < 4; ++mi) {
        const int n = mi * 16 + lo;
        const bool valid = (n < 49);
        const float* row = xw + n * 192;
#pragma unroll
        for (int kk = 0; kk < 6; ++kk) {
            floatv4 f0 = {0.f, 0.f, 0.f, 0.f}, f1 = {0.f, 0.f, 0.f, 0.f};
            if (valid) {
                f0 = *(const floatv4*)(row + kk * 32 + hi * 8);
                f1 = *(const floatv4*)(row + kk * 32 + hi * 8 + 4);
            }
            bf16x8 a;
            a[0] = (bf16)f0[0]; a[1] = (bf16)f0[1]; a[2] = (bf16)f0[2]; a[3] = (bf16)f0[3];
            a[4] = (bf16)f1[0]; a[5] = (bf16)f1[1]; a[6] = (bf16)f1[2]; a[7] = (bf16)f1[3];
            afr[mi][kk] = a;
        }
    }

#pragma unroll 1
    for (int nj = 0; nj < 6; ++nj) {
        const int o = wv * 96 + nj * 16 + lo;   // output column 0..575
        bf16x8 bfr[6];
#pragma unroll
        for (int kk = 0; kk < 6; ++kk)
            bfr[kk] = *(const bf16x8*)(qkv_wb + o * 192 + kk * 32 + hi * 8);
        f32x4 acc[4];
#pragma unroll
        for (int mi = 0; mi < 4; ++mi) acc[mi] = (f32x4){0.f, 0.f, 0.f, 0.f};
#pragma unroll
        for (int kk = 0; kk < 6; ++kk)
#pragma unroll
            for (int mi = 0; mi < 4; ++mi)
                acc[mi] = __builtin_amdgcn_mfma_f32_16x16x32_bf16(
                    afr[mi][kk], bfr[kk], acc[mi], 0, 0, 0);

        const float bias = qkv_b[o];
        const int sec = o / 192;            // 0=q 1=k 2=v (uniform per tile)
        const int oc  = o % 192;
        const int hh  = oc >> 5;
        const int dd  = oc & 31;
#pragma unroll
        for (int mi = 0; mi < 4; ++mi)
#pragma unroll
            for (int r = 0; r < 4; ++r) {
                const int n = mi * 16 + hi * 4 + r;
                float v = acc[mi][r] + bias;
                if (sec == 0)      sm.q[hh][n][dd]  = (bf16)(v * QK_SCALE);
                else if (sec == 1) sm.k[hh][n][dd]  = (bf16)v;
                else               sm.vt[hh][dd][n] = (bf16)v;
            }
    }
    __syncthreads();

    // ================= Phase 2: attention, head h = wave id =================
    {
        const int h = wv;
        f32x4 s[4][4];
#pragma unroll
        for (int mi = 0; mi < 4; ++mi)
#pragma unroll
            for (int nt = 0; nt < 4; ++nt) s[mi][nt] = (f32x4){0.f, 0.f, 0.f, 0.f};

        bf16x8 qa[4], kb[4];
#pragma unroll
        for (int mi = 0; mi < 4; ++mi)
            qa[mi] = *(const bf16x8*)(&sm.q[h][mi * 16 + lo][hi * 8]);
#pragma unroll
        for (int nt = 0; nt < 4; ++nt)
            kb[nt] = *(const bf16x8*)(&sm.k[h][nt * 16 + lo][hi * 8]);
#pragma unroll
        for (int mi = 0; mi < 4; ++mi)
#pragma unroll
            for (int nt = 0; nt < 4; ++nt)
                s[mi][nt] = __builtin_amdgcn_mfma_f32_16x16x32_bf16(
                    qa[mi], kb[nt], s[mi][nt], 0, 0, 0);

        // add rpb + window mask; kill padded key columns
        const float* mk = mask + (size_t)(b & 63) * 2401;
        const float* rb = rpbx + h * 2401;
#pragma unroll
        for (int nt = 0; nt < 4; ++nt) {
            const int j = nt * 16 + lo;
#pragma unroll
            for (int mi = 0; mi < 4; ++mi)
#pragma unroll
                for (int r = 0; r < 4; ++r) {
                    const int i = mi * 16 + hi * 4 + r;
                    float sv = s[mi][nt][r];
                    if (j >= 49) sv = -1e30f;
                    else if (i < 49) sv += rb[i * 49 + j] + mk[i * 49 + j];
                    s[mi][nt][r] = sv;
                }
        }

        // softmax over j (64 cols = 4 regs x 16 lanes sharing hi)
#pragma unroll
        for (int mi = 0; mi < 4; ++mi)
#pragma unroll
            for (int r = 0; r < 4; ++r) {
                float m = fmaxf(fmaxf(s[mi][0][r], s[mi][1][r]),
                                fmaxf(s[mi][2][r], s[mi][3][r]));
                m = fmaxf(m, __shfl_xor(m, 1));
                m = fmaxf(m, __shfl_xor(m, 2));
                m = fmaxf(m, __shfl_xor(m, 4));
                m = fmaxf(m, __shfl_xor(m, 8));
                float sum = 0.f;
#pragma unroll
                for (int nt = 0; nt < 4; ++nt) {
                    float p = __expf(s[mi][nt][r] - m);
                    s[mi][nt][r] = p;
                    sum += p;
                }
                sum += __shfl_xor(sum, 1);
                sum += __shfl_xor(sum, 2);
                sum += __shfl_xor(sum, 4);
                sum += __shfl_xor(sum, 8);
                const float inv = 1.0f / sum;
#pragma unroll
                for (int nt = 0; nt < 4; ++nt) s[mi][nt][r] *= inv;
            }

        // PV: O_h = P(49x64) @ V_h(64x32), P staged per-wave in 32-col chunks
        f32x4 oacc[4][2];
#pragma unroll
        for (int mi = 0; mi < 4; ++mi)
#pragma unroll
            for (int nd = 0; nd < 2; ++nd) oacc[mi][nd] = (f32x4){0.f, 0.f, 0.f, 0.f};

#pragma unroll 1
        for (int kk = 0; kk < 2; ++kk) {
            // store chunk cols [kk*32, kk*32+32)
#pragma unroll
            for (int mi = 0; mi < 4; ++mi)
#pragma unroll
                for (int c = 0; c < 2; ++c) {
                    const int nt = kk * 2 + c;
#pragma unroll
                    for (int r = 0; r < 4; ++r) {
                        const int i = mi * 16 + hi * 4 + r;
                        sm.p[h][i][c * 16 + lo] = (bf16)s[mi][nt][r];
                    }
                }
            bf16x8 pa[4];
#pragma unroll
            for (int mi = 0; mi < 4; ++mi)
                pa[mi] = *(const bf16x8*)(&sm.p[h][mi * 16 + lo][hi * 8]);
#pragma unroll
            for (int nd = 0; nd < 2; ++nd) {
                bf16x8 vb = *(const bf16x8*)(&sm.vt[h][nd * 16 + lo][kk * 32 + hi * 8]);
#pragma unroll
                for (int mi = 0; mi < 4; ++mi)
                    oacc[mi][nd] = __builtin_amdgcn_mfma_f32_16x16x32_bf16(
                        pa[mi], vb, oacc[mi][nd], 0, 0, 0);
            }
        }

        // scatter head output into ao
#pragma unroll
        for (int mi = 0; mi < 4; ++mi)
#pragma unroll
            for (int nd = 0; nd < 2; ++nd)
#pragma unroll
                for (int r = 0; r < 4; ++r) {
                    const int n = mi * 16 + hi * 4 + r;
                    sm.ao[n][h * 32 + nd * 16 + lo] = (bf16)oacc[mi][nd][r];
                }
    }
    __syncthreads();

    // ================= Phase 3: out = ao @ out_w^T + out_b =================
    f32x4 facc[4][2];
#pragma unroll
    for (int mi = 0; mi < 4; ++mi)
#pragma unroll
        for (int t = 0; t < 2; ++t) facc[mi][t] = (f32x4){0.f, 0.f, 0.f, 0.f};

#pragma unroll 1
    for (int kk = 0; kk < 6; ++kk) {
        bf16x8 fa[4];
#pragma unroll
        for (int mi = 0; mi < 4; ++mi)
            fa[mi] = *(const bf16x8*)(&sm.ao[mi * 16 + lo][kk * 32 + hi * 8]);
#pragma unroll
        for (int t = 0; t < 2; ++t) {
            const int o2 = (wv * 2 + t) * 16 + lo;
            bf16x8 fb = *(const bf16x8*)(out_wb + o2 * 192 + kk * 32 + hi * 8);
#pragma unroll
            for (int mi = 0; mi < 4; ++mi)
                facc[mi][t] = __builtin_amdgcn_mfma_f32_16x16x32_bf16(
                    fa[mi], fb, facc[mi][t], 0, 0, 0);
        }
    }

    float* ow = out + (size_t)b * 9408;
#pragma unroll
    for (int t = 0; t < 2; ++t) {
        const int o2 = (wv * 2 + t) * 16 + lo;
        const float ob = out_b[o2];
#pragma unroll
        for (int mi = 0; mi < 4; ++mi)
#pragma unroll
            for (int r = 0; r < 4; ++r) {
                const int n = mi * 16 + hi * 4 + r;
                if (n < 49) ow[n * 192 + o2] = facc[mi][t][r] + ob;
            }
    }
}

extern "C" void kernel_launch(void* const* d_in, const int* in_sizes, int n_in,
                              void* d_out, int out_size, void* d_ws, size_t ws_size,
                              hipStream_t stream) {
    const float* x      = (const float*)d_in[0];
    const float* mask   = (const float*)d_in[1];
    const float* qkv_w  = (const float*)d_in[2];
    const float* qkv_b  = (const float*)d_in[3];
    const float* out_w  = (const float*)d_in[4];
    const float* out_b  = (const float*)d_in[5];
    const float* rpb    = (const float*)d_in[6];
    float* out          = (float*)d_out;

    char* ws = (char*)d_ws;
    bf16*  qkv_wb = (bf16*)ws;                          // 110592 * 2 = 221184 B
    bf16*  out_wb = (bf16*)(ws + 221184);               //  36864 * 2 =  73728 B
    float* rpbx   = (float*)(ws + 221184 + 73728);      //  14406 * 4 =  57624 B

    hipLaunchKernelGGL(wmsa_prep, dim3(432), dim3(256), 0, stream,
                       qkv_w, out_w, rpb, qkv_wb, out_wb, rpbx);
    hipLaunchKernelGGL(wmsa_main, dim3(4096), dim3(384), 0, stream,
                       x, mask, qkv_b, out_b, qkv_wb, out_wb, rpbx, out);
}